// Round 15
// baseline (531.317 us; speedup 1.0000x reference)
//
#include <hip/hip_runtime.h>
#include <hip/hip_bf16.h>

#define N_NODES 131072
#define B_GRAPHS 256
#define NPG 512
#define KNN 7
#define HEADS 4

using f4 = __attribute__((ext_vector_type(4))) float;
using short8 = __attribute__((ext_vector_type(8))) short;  // 8 bf16 (4 VGPRs)

__device__ __forceinline__ unsigned short f2bf(float f) {   // RNE f32->bf16
    unsigned u = __builtin_bit_cast(unsigned, f);
    u += 0x7FFFu + ((u >> 16) & 1u);
    return (unsigned short)(u >> 16);
}

// 8 packed bf16 (uint4) -> 8 f32 in sequential channel order, 8 VALU ops.
__device__ __forceinline__ void u4_to_f8(const uint4 u, f4* out) {
    out[0][0] = __builtin_bit_cast(float, u.x << 16);
    out[0][1] = __builtin_bit_cast(float, u.x & 0xFFFF0000u);
    out[0][2] = __builtin_bit_cast(float, u.y << 16);
    out[0][3] = __builtin_bit_cast(float, u.y & 0xFFFF0000u);
    out[1][0] = __builtin_bit_cast(float, u.z << 16);
    out[1][1] = __builtin_bit_cast(float, u.z & 0xFFFF0000u);
    out[1][2] = __builtin_bit_cast(float, u.w << 16);
    out[1][3] = __builtin_bit_cast(float, u.w & 0xFFFF0000u);
}

__device__ __forceinline__ unsigned med3u(unsigned a, unsigned b, unsigned c) {
    unsigned r;
    asm("v_med3_u32 %0, %1, %2, %3" : "=v"(r) : "v"(a), "v"(b), "v"(c));
    return r;
}

// insert key into ascending top-7: valid because b[] is sorted, so
// max(b[i-1], min(b[i], k)) == med3(b[i-1], b[i], k). 1 umin + 6 med3 = 7 ops.
#define INS7(B, KEY) { \
    const unsigned _k = (KEY); \
    const unsigned n0 = min(B[0], _k); \
    const unsigned n1 = med3u(B[0], B[1], _k); \
    const unsigned n2 = med3u(B[1], B[2], _k); \
    const unsigned n3 = med3u(B[2], B[3], _k); \
    const unsigned n4 = med3u(B[3], B[4], _k); \
    const unsigned n5 = med3u(B[4], B[5], _k); \
    const unsigned n6 = med3u(B[5], B[6], _k); \
    B[0]=n0; B[1]=n1; B[2]=n2; B[3]=n3; B[4]=n4; B[5]=n5; B[6]=n6; }

// ---------------------------------------------------------------------------
// Kernel 1: kNN, 4-way candidate split (verified round 12).
// ---------------------------------------------------------------------------
__global__ __launch_bounds__(512) void knn_kernel(const float* __restrict__ pos,
                                                  int* __restrict__ knn) {
    __shared__ f4 sp[NPG];
    __shared__ unsigned mk[3][128][7];
    const int tid = threadIdx.x;
    const int g = blockIdx.x >> 2;
    const int qh = blockIdx.x & 3;
    const int ch = tid >> 7;                 // candidate chunk 0..3
    const int ql = tid & 127;
    const int q = qh * 128 + ql;             // local query index

    const float* p = pos + (size_t)g * NPG * 3;
    {
        f4 v; v[0] = p[tid * 3 + 0]; v[1] = p[tid * 3 + 1]; v[2] = p[tid * 3 + 2]; v[3] = 0.f;
        sp[tid] = v;
    }
    __syncthreads();

    const f4 qp = sp[q];
    unsigned b[7];
#pragma unroll
    for (int i = 0; i < 7; ++i) b[i] = 0xFFFFFFFFu;

    const int j0 = ch << 7;
#pragma unroll 8
    for (int j = 0; j < 128; ++j) {
        const int jj = j0 + j;                  // wave-uniform
        const f4 c = sp[jj];                    // LDS broadcast
        const float dx = qp[0] - c[0];
        const float dy = qp[1] - c[1];
        const float dz = qp[2] - c[2];
        const float d2 = dx * dx + dy * dy + dz * dz;
        unsigned key = (__builtin_bit_cast(unsigned, d2) & 0xFFFFFE00u) | (unsigned)jj;
        key = (jj == q) ? 0xFFFFFFFFu : key;    // no self-loop
        INS7(b, key)
    }

    if (ch != 0) {
        unsigned* m = mk[ch - 1][ql];
#pragma unroll
        for (int i = 0; i < 7; ++i) m[i] = b[i];
    }
    __syncthreads();
    if (ch == 0) {
#pragma unroll
        for (int cc = 0; cc < 3; ++cc) {
            const unsigned* m = mk[cc][ql];
#pragma unroll
            for (int i = 0; i < 7; ++i) INS7(b, m[i])
        }
        const int base = (g * NPG + q) * KNN;
        const int off = g * NPG;
#pragma unroll
        for (int i = 0; i < 7; ++i) knn[base + i] = off + (int)(b[i] & 0x1FFu);
    }
}
#undef INS7

// ---------------------------------------------------------------------------
// Kernel 2: fused lin1. Both xl1 and xr1 -> bf16 (validated round 13).
// ---------------------------------------------------------------------------
__global__ __launch_bounds__(256) void lin1_kernel(const float* __restrict__ x,
                                                   const float* __restrict__ Wl,
                                                   const float* __restrict__ bl,
                                                   const float* __restrict__ Wr,
                                                   const float* __restrict__ br,
                                                   unsigned short* __restrict__ xl1b,
                                                   unsigned short* __restrict__ xr1b) {
    const int idx = blockIdx.x * 256 + threadIdx.x;   // N*16
    const int c4 = idx & 15;
    const size_t node = (size_t)(idx >> 4);
    const float* xrow = x + node * 10;
    f4 al = ((const f4*)bl)[c4];
    f4 ar = ((const f4*)br)[c4];
#pragma unroll
    for (int k = 0; k < 10; ++k) {
        const float xv = xrow[k];
        al += xv * ((const f4*)(Wl + k * 64))[c4];
        ar += xv * ((const f4*)(Wr + k * 64))[c4];
    }
    uint2 pl, pr;
    pl.x = (unsigned)f2bf(al[0]) | ((unsigned)f2bf(al[1]) << 16);
    pl.y = (unsigned)f2bf(al[2]) | ((unsigned)f2bf(al[3]) << 16);
    pr.x = (unsigned)f2bf(ar[0]) | ((unsigned)f2bf(ar[1]) << 16);
    pr.y = (unsigned)f2bf(ar[2]) | ((unsigned)f2bf(ar[3]) << 16);
    ((uint2*)xl1b)[node * 16 + c4] = pl;
    ((uint2*)xr1b)[node * 16 + c4] = pr;
}

// ---------------------------------------------------------------------------
// Kernel 3: GATv2 layer-1 aggregation — round-12/14 structure (one thread per
// (node, head), 16 ch, two-pass), pair-converts + <=64 VGPR target for
// 8 waves/SIMD. XCD-swizzled.
// ---------------------------------------------------------------------------
__global__ __launch_bounds__(256, 8) void agg1_kernel(const unsigned short* __restrict__ xl1b,
                                                      const unsigned short* __restrict__ xr1b,
                                                      const int* __restrict__ knn,
                                                      const float* __restrict__ att,
                                                      const float* __restrict__ bias,
                                                      unsigned short* __restrict__ h1b) {
    const int x = blockIdx.x & 7;
    const int i = blockIdx.x >> 3;
    const int graph = x * 32 + (i >> 3);
    const int sub = i & 7;
    const int tid = threadIdx.x;
    const int h = tid & 3;
    const size_t node = (size_t)graph * NPG + sub * 64 + (tid >> 2);

    const int* nb = knn + node * KNN;
    int j[KNN];
#pragma unroll
    for (int k = 0; k < KNN; ++k) j[k] = nb[k];

    f4 xr4[4], at4[4];
    {
        const uint4* xrp = (const uint4*)(xr1b + node * 64 + h * 16);
        u4_to_f8(xrp[0], &xr4[0]);
        u4_to_f8(xrp[1], &xr4[2]);
        const f4* atp = (const f4*)(att + h * 16);
#pragma unroll
        for (int i2 = 0; i2 < 4; ++i2) at4[i2] = atp[i2];
    }

    float alpha[KNN];
#pragma unroll
    for (int k = 0; k < KNN; ++k) {
        const uint4* xlp = (const uint4*)(xl1b + (size_t)j[k] * 64 + h * 16);
        f4 xlv[4];
        u4_to_f8(xlp[0], &xlv[0]);
        u4_to_f8(xlp[1], &xlv[2]);
        float s = 0.f;
#pragma unroll
        for (int i2 = 0; i2 < 4; ++i2) {
            const f4 m = xlv[i2] + xr4[i2];
#pragma unroll
            for (int c = 0; c < 4; ++c) {
                float mm = m[c];
                mm = mm > 0.f ? mm : 0.2f * mm;   // leaky_relu(., 0.2)
                s += mm * at4[i2][c];
            }
        }
        alpha[k] = s;
    }
    float amax = alpha[0];
#pragma unroll
    for (int k = 1; k < KNN; ++k) amax = fmaxf(amax, alpha[k]);
    float e[KNN];
    float denom = 0.f;
#pragma unroll
    for (int k = 0; k < KNN; ++k) { e[k] = expf(alpha[k] - amax); denom += e[k]; }
    const float rd = 1.f / denom;

    f4 o4[4];
#pragma unroll
    for (int i2 = 0; i2 < 4; ++i2) o4[i2] = 0.f;
#pragma unroll
    for (int k = 0; k < KNN; ++k) {
        const uint4* xlp = (const uint4*)(xl1b + (size_t)j[k] * 64 + h * 16);
        f4 xlv[4];
        u4_to_f8(xlp[0], &xlv[0]);
        u4_to_f8(xlp[1], &xlv[2]);
#pragma unroll
        for (int i2 = 0; i2 < 4; ++i2) o4[i2] += e[k] * xlv[i2];
    }
    const f4* bp = (const f4*)(bias + h * 16);
    short8 r0, r1;
#pragma unroll
    for (int i2 = 0; i2 < 4; ++i2) {
        const f4 v = o4[i2] * rd + bp[i2];
#pragma unroll
        for (int c = 0; c < 4; ++c) {
            const unsigned short bv = f2bf(v[c]);
            const int e4 = i2 * 4 + c;
            if (e4 < 8) r0[e4] = (short)bv; else r1[e4 - 8] = (short)bv;
        }
    }
    short8* hp = (short8*)(h1b + node * 64 + h * 16);
    hp[0] = r0;
    hp[1] = r1;
}

// ---------------------------------------------------------------------------
// Kernel 4a: pack Wl2||Wr2 into bf16 MFMA B-fragment layout.
// ---------------------------------------------------------------------------
__global__ __launch_bounds__(256) void wprep_kernel(const float* __restrict__ Wl,
                                                    const float* __restrict__ Wr,
                                                    unsigned short* __restrict__ wbf) {
    const int t = blockIdx.x * 256 + threadIdx.x;   // 64*256 = 16384
    const int k = t >> 8;
    const int n = t & 255;
    const float v = (n < 128) ? Wl[k * 128 + n] : Wr[k * 128 + (n - 128)];
    wbf[((k >> 3) * 256 + n) * 8 + (k & 7)] = f2bf(v);
}

// ---------------------------------------------------------------------------
// Kernel 4b: lin2 via MFMA (mapping verified round 8). Outputs bf16.
// ---------------------------------------------------------------------------
__global__ __launch_bounds__(256) void lin2_kernel(const unsigned short* __restrict__ h1b,
                                                   const unsigned short* __restrict__ wbf,
                                                   const float* __restrict__ bl,
                                                   const float* __restrict__ br,
                                                   unsigned short* __restrict__ xl2b,
                                                   unsigned short* __restrict__ xr2b) {
    const int tid = threadIdx.x;
    const int lane = tid & 63;
    const int w = tid >> 6;
    const size_t node0 = (size_t)blockIdx.x * 16;
    const int lm = lane & 15, lk = lane >> 4;

    const short8* hp = (const short8*)h1b;
    const short8 a0 = hp[(node0 + lm) * 8 + lk];
    const short8 a1 = hp[(node0 + lm) * 8 + lk + 4];

    const short8* wp = (const short8*)wbf;
#pragma unroll
    for (int t = 0; t < 4; ++t) {
        const int col = w * 64 + t * 16 + lm;
        const float bias = (col < 128) ? bl[col] : br[col - 128];
        f4 acc = {bias, bias, bias, bias};
        const short8 b0 = wp[lk * 256 + col];
        const short8 b1 = wp[(lk + 4) * 256 + col];
        acc = __builtin_amdgcn_mfma_f32_16x16x32_bf16(a0, b0, acc, 0, 0, 0);
        acc = __builtin_amdgcn_mfma_f32_16x16x32_bf16(a1, b1, acc, 0, 0, 0);
        unsigned short* dst = (col < 128) ? (xl2b + col) : (xr2b + (col - 128));
#pragma unroll
        for (int r = 0; r < 4; ++r)
            dst[(node0 + lk * 4 + r) * 128] = f2bf(acc[r]);
    }
}

// ---------------------------------------------------------------------------
// Kernel 5: GATv2 layer-2 aggregation + pooling — round-12/14 structure
// (one thread per (node, head, half), 16 ch, two-pass, butterfly pool),
// pair-converts + <=64 VGPR target for 8 waves/SIMD. XCD-swizzled.
// ---------------------------------------------------------------------------
__global__ __launch_bounds__(256, 8) void agg2_pool_kernel(const unsigned short* __restrict__ xl2b,
                                                           const unsigned short* __restrict__ xr2b,
                                                           const int* __restrict__ knn,
                                                           const float* __restrict__ att,
                                                           float* __restrict__ partial) {
    const int x = blockIdx.x & 7;
    const int i = blockIdx.x >> 3;
    const int graph = x * 32 + (i >> 4);
    const int sub = i & 15;
    const int tid = threadIdx.x;
    const int lane = tid & 63;
    const int wv = tid >> 6;
    const int n8 = lane >> 3;
    const int h = (lane >> 1) & 3;
    const int half = lane & 1;
    const size_t node = (size_t)graph * NPG + sub * 32 + wv * 8 + n8;
    const int co = h * 32 + half * 16;

    const int* nb = knn + node * KNN;
    int j[KNN];
#pragma unroll
    for (int k = 0; k < KNN; ++k) j[k] = nb[k];

    f4 xr4[4], at4[4];
    {
        const uint4* xrp = (const uint4*)(xr2b + node * 128 + co);
        u4_to_f8(xrp[0], &xr4[0]);
        u4_to_f8(xrp[1], &xr4[2]);
        const f4* atp = (const f4*)(att + co);
#pragma unroll
        for (int i2 = 0; i2 < 4; ++i2) at4[i2] = atp[i2];
    }

    float alpha[KNN];
#pragma unroll
    for (int k = 0; k < KNN; ++k) {
        const uint4* xlp = (const uint4*)(xl2b + (size_t)j[k] * 128 + co);
        f4 xlv[4];
        u4_to_f8(xlp[0], &xlv[0]);
        u4_to_f8(xlp[1], &xlv[2]);
        float s = 0.f;
#pragma unroll
        for (int i2 = 0; i2 < 4; ++i2) {
            const f4 m = xlv[i2] + xr4[i2];
#pragma unroll
            for (int c = 0; c < 4; ++c) {
                float mm = m[c];
                mm = mm > 0.f ? mm : 0.2f * mm;
                s += mm * at4[i2][c];
            }
        }
        alpha[k] = s + __shfl_xor(s, 1);
    }
    float amax = alpha[0];
#pragma unroll
    for (int k = 1; k < KNN; ++k) amax = fmaxf(amax, alpha[k]);
    float e[KNN];
    float denom = 0.f;
#pragma unroll
    for (int k = 0; k < KNN; ++k) { e[k] = expf(alpha[k] - amax); denom += e[k]; }
    const float rd = 1.f / denom;

    f4 o4[4];
#pragma unroll
    for (int i2 = 0; i2 < 4; ++i2) o4[i2] = 0.f;
#pragma unroll
    for (int k = 0; k < KNN; ++k) {
        const uint4* xlp = (const uint4*)(xl2b + (size_t)j[k] * 128 + co);
        f4 xlv[4];
        u4_to_f8(xlp[0], &xlv[0]);
        u4_to_f8(xlp[1], &xlv[2]);
#pragma unroll
        for (int i2 = 0; i2 < 4; ++i2) o4[i2] += e[k] * xlv[i2];
    }
#pragma unroll
    for (int i2 = 0; i2 < 4; ++i2) o4[i2] *= rd;

#pragma unroll
    for (int m = 8; m <= 32; m <<= 1) {
#pragma unroll
        for (int i2 = 0; i2 < 4; ++i2) {
#pragma unroll
            for (int c = 0; c < 4; ++c) o4[i2][c] += __shfl_xor(o4[i2][c], m);
        }
    }
    if (n8 == 0) {
        f4* pp = (f4*)(partial + ((size_t)(graph * 16 + sub) * 4 + wv) * 128 + co);
#pragma unroll
        for (int i2 = 0; i2 < 4; ++i2) pp[i2] = o4[i2];
    }
}

// ---------------------------------------------------------------------------
// Kernel 6: stage-2 pool. One block per graph; 64 partials, /NPG, +bias2.
// ---------------------------------------------------------------------------
__global__ __launch_bounds__(128) void pool2_kernel(const float* __restrict__ partial,
                                                    const float* __restrict__ bias,
                                                    float* __restrict__ out) {
    const int g = blockIdx.x;
    const int c = threadIdx.x;
    float s = 0.f;
#pragma unroll
    for (int b = 0; b < 64; ++b) s += partial[(size_t)(g * 64 + b) * 128 + c];
    out[g * 128 + c] = s * (1.f / 512.f) + bias[c];
}

extern "C" void kernel_launch(void* const* d_in, const int* in_sizes, int n_in,
                              void* d_out, int out_size, void* d_ws, size_t ws_size,
                              hipStream_t stream) {
    const float* pos   = (const float*)d_in[0];
    const float* x     = (const float*)d_in[1];
    const float* Wl1   = (const float*)d_in[3];
    const float* bl1   = (const float*)d_in[4];
    const float* Wr1   = (const float*)d_in[5];
    const float* br1   = (const float*)d_in[6];
    const float* att1  = (const float*)d_in[7];
    const float* bias1 = (const float*)d_in[8];
    const float* Wl2   = (const float*)d_in[9];
    const float* bl2   = (const float*)d_in[10];
    const float* Wr2   = (const float*)d_in[11];
    const float* br2   = (const float*)d_in[12];
    const float* att2  = (const float*)d_in[13];
    const float* bias2 = (const float*)d_in[14];
    float* out = (float*)d_out;

    // Workspace layout (liveness-overlapped):
    //   [0,          3670016)  knn [N][7] i32                    (live: all)
    //   [3670016,   20447232)  xl1b bf16 [N][64]  (dead after agg1)
    //   [20447232,  37224448)  xr1b bf16 [N][64]  (dead after agg1)
    //   [37224448,  54001664)  h1b  bf16 [N][64]  (dead after lin2;
    //        partial [16384][128] f32 = 8.4MB overlays here)
    //   [54001664,  54034432)  wbf bf16 32KB
    //   [88080384, 121634816)  xl2b bf16 [N][128]
    //   [121634816,155189248)  xr2b bf16 [N][128]
    char* ws = (char*)d_ws;
    int*            knn  = (int*)(ws + 0);
    unsigned short* xl1b = (unsigned short*)(ws + 3670016);
    unsigned short* xr1b = (unsigned short*)(ws + 20447232);
    unsigned short* h1b  = (unsigned short*)(ws + 37224448);
    unsigned short* wbf  = (unsigned short*)(ws + 54001664);
    unsigned short* xl2b = (unsigned short*)(ws + 88080384);
    unsigned short* xr2b = (unsigned short*)(ws + 121634816);
    float*          partial = (float*)(ws + 37224448); // over dead h1b

    knn_kernel<<<B_GRAPHS * 4, 512, 0, stream>>>(pos, knn);
    lin1_kernel<<<(N_NODES * 16) / 256, 256, 0, stream>>>(x, Wl1, bl1, Wr1, br1, xl1b, xr1b);
    wprep_kernel<<<64, 256, 0, stream>>>(Wl2, Wr2, wbf);
    agg1_kernel<<<(N_NODES * 4) / 256, 256, 0, stream>>>(xl1b, xr1b, knn, att1, bias1, h1b);
    lin2_kernel<<<N_NODES / 16, 256, 0, stream>>>(h1b, wbf, bl2, br2, xl2b, xr2b);
    agg2_pool_kernel<<<N_NODES / 32, 256, 0, stream>>>(xl2b, xr2b, knn, att2, partial);
    pool2_kernel<<<B_GRAPHS, 128, 0, stream>>>(partial, bias2, out);
}

// Round 16
// 153.455 us; speedup vs baseline: 3.4624x; 3.4624x over previous
//
#include <hip/hip_runtime.h>
#include <hip/hip_bf16.h>

#define N_NODES 131072
#define B_GRAPHS 256
#define NPG 512
#define KNN 7
#define HEADS 4

using f4 = __attribute__((ext_vector_type(4))) float;
using short8 = __attribute__((ext_vector_type(8))) short;  // 8 bf16 (4 VGPRs)

__device__ __forceinline__ unsigned short f2bf(float f) {   // RNE f32->bf16
    unsigned u = __builtin_bit_cast(unsigned, f);
    u += 0x7FFFu + ((u >> 16) & 1u);
    return (unsigned short)(u >> 16);
}

// 8 packed bf16 (uint4) -> 8 f32 in sequential channel order, 8 VALU ops.
__device__ __forceinline__ void u4_to_f8(const uint4 u, f4* out) {
    out[0][0] = __builtin_bit_cast(float, u.x << 16);
    out[0][1] = __builtin_bit_cast(float, u.x & 0xFFFF0000u);
    out[0][2] = __builtin_bit_cast(float, u.y << 16);
    out[0][3] = __builtin_bit_cast(float, u.y & 0xFFFF0000u);
    out[1][0] = __builtin_bit_cast(float, u.z << 16);
    out[1][1] = __builtin_bit_cast(float, u.z & 0xFFFF0000u);
    out[1][2] = __builtin_bit_cast(float, u.w << 16);
    out[1][3] = __builtin_bit_cast(float, u.w & 0xFFFF0000u);
}

__device__ __forceinline__ unsigned med3u(unsigned a, unsigned b, unsigned c) {
    unsigned r;
    asm("v_med3_u32 %0, %1, %2, %3" : "=v"(r) : "v"(a), "v"(b), "v"(c));
    return r;
}

// insert key into ascending top-7: valid because b[] is sorted, so
// max(b[i-1], min(b[i], k)) == med3(b[i-1], b[i], k). 1 umin + 6 med3 = 7 ops.
#define INS7(B, KEY) { \
    const unsigned _k = (KEY); \
    const unsigned n0 = min(B[0], _k); \
    const unsigned n1 = med3u(B[0], B[1], _k); \
    const unsigned n2 = med3u(B[1], B[2], _k); \
    const unsigned n3 = med3u(B[2], B[3], _k); \
    const unsigned n4 = med3u(B[3], B[4], _k); \
    const unsigned n5 = med3u(B[4], B[5], _k); \
    const unsigned n6 = med3u(B[5], B[6], _k); \
    B[0]=n0; B[1]=n1; B[2]=n2; B[3]=n3; B[4]=n4; B[5]=n5; B[6]=n6; }

// ---------------------------------------------------------------------------
// Kernel 1: kNN, 4-way candidate split (verified round 12).
// ---------------------------------------------------------------------------
__global__ __launch_bounds__(512) void knn_kernel(const float* __restrict__ pos,
                                                  int* __restrict__ knn) {
    __shared__ f4 sp[NPG];
    __shared__ unsigned mk[3][128][7];
    const int tid = threadIdx.x;
    const int g = blockIdx.x >> 2;
    const int qh = blockIdx.x & 3;
    const int ch = tid >> 7;                 // candidate chunk 0..3
    const int ql = tid & 127;
    const int q = qh * 128 + ql;             // local query index

    const float* p = pos + (size_t)g * NPG * 3;
    {
        f4 v; v[0] = p[tid * 3 + 0]; v[1] = p[tid * 3 + 1]; v[2] = p[tid * 3 + 2]; v[3] = 0.f;
        sp[tid] = v;
    }
    __syncthreads();

    const f4 qp = sp[q];
    unsigned b[7];
#pragma unroll
    for (int i = 0; i < 7; ++i) b[i] = 0xFFFFFFFFu;

    const int j0 = ch << 7;
#pragma unroll 8
    for (int j = 0; j < 128; ++j) {
        const int jj = j0 + j;                  // wave-uniform
        const f4 c = sp[jj];                    // LDS broadcast
        const float dx = qp[0] - c[0];
        const float dy = qp[1] - c[1];
        const float dz = qp[2] - c[2];
        const float d2 = dx * dx + dy * dy + dz * dz;
        unsigned key = (__builtin_bit_cast(unsigned, d2) & 0xFFFFFE00u) | (unsigned)jj;
        key = (jj == q) ? 0xFFFFFFFFu : key;    // no self-loop
        INS7(b, key)
    }

    if (ch != 0) {
        unsigned* m = mk[ch - 1][ql];
#pragma unroll
        for (int i = 0; i < 7; ++i) m[i] = b[i];
    }
    __syncthreads();
    if (ch == 0) {
#pragma unroll
        for (int cc = 0; cc < 3; ++cc) {
            const unsigned* m = mk[cc][ql];
#pragma unroll
            for (int i = 0; i < 7; ++i) INS7(b, m[i])
        }
        const int base = (g * NPG + q) * KNN;
        const int off = g * NPG;
#pragma unroll
        for (int i = 0; i < 7; ++i) knn[base + i] = off + (int)(b[i] & 0x1FFu);
    }
}
#undef INS7

// ---------------------------------------------------------------------------
// Kernel 2: fused lin1. Both xl1 and xr1 -> bf16 (validated round 13).
// ---------------------------------------------------------------------------
__global__ __launch_bounds__(256) void lin1_kernel(const float* __restrict__ x,
                                                   const float* __restrict__ Wl,
                                                   const float* __restrict__ bl,
                                                   const float* __restrict__ Wr,
                                                   const float* __restrict__ br,
                                                   unsigned short* __restrict__ xl1b,
                                                   unsigned short* __restrict__ xr1b) {
    const int idx = blockIdx.x * 256 + threadIdx.x;   // N*16
    const int c4 = idx & 15;
    const size_t node = (size_t)(idx >> 4);
    const float* xrow = x + node * 10;
    f4 al = ((const f4*)bl)[c4];
    f4 ar = ((const f4*)br)[c4];
#pragma unroll
    for (int k = 0; k < 10; ++k) {
        const float xv = xrow[k];
        al += xv * ((const f4*)(Wl + k * 64))[c4];
        ar += xv * ((const f4*)(Wr + k * 64))[c4];
    }
    uint2 pl, pr;
    pl.x = (unsigned)f2bf(al[0]) | ((unsigned)f2bf(al[1]) << 16);
    pl.y = (unsigned)f2bf(al[2]) | ((unsigned)f2bf(al[3]) << 16);
    pr.x = (unsigned)f2bf(ar[0]) | ((unsigned)f2bf(ar[1]) << 16);
    pr.y = (unsigned)f2bf(ar[2]) | ((unsigned)f2bf(ar[3]) << 16);
    ((uint2*)xl1b)[node * 16 + c4] = pl;
    ((uint2*)xr1b)[node * 16 + c4] = pr;
}

// ---------------------------------------------------------------------------
// Kernel 3: GATv2 layer-1 aggregation — round-12/14 structure (one thread per
// (node, head), 16 ch, two-pass), pair-converts. XCD-swizzled.
// NOTE: no min-waves launch bound — forcing 8 waves/EU spilled (round 15:
// 532MB scratch writes, 280µs). Let the allocator pick (~72 VGPR, 4 waves).
// ---------------------------------------------------------------------------
__global__ __launch_bounds__(256) void agg1_kernel(const unsigned short* __restrict__ xl1b,
                                                   const unsigned short* __restrict__ xr1b,
                                                   const int* __restrict__ knn,
                                                   const float* __restrict__ att,
                                                   const float* __restrict__ bias,
                                                   unsigned short* __restrict__ h1b) {
    const int x = blockIdx.x & 7;
    const int i = blockIdx.x >> 3;
    const int graph = x * 32 + (i >> 3);
    const int sub = i & 7;
    const int tid = threadIdx.x;
    const int h = tid & 3;
    const size_t node = (size_t)graph * NPG + sub * 64 + (tid >> 2);

    const int* nb = knn + node * KNN;
    int j[KNN];
#pragma unroll
    for (int k = 0; k < KNN; ++k) j[k] = nb[k];

    f4 xr4[4], at4[4];
    {
        const uint4* xrp = (const uint4*)(xr1b + node * 64 + h * 16);
        u4_to_f8(xrp[0], &xr4[0]);
        u4_to_f8(xrp[1], &xr4[2]);
        const f4* atp = (const f4*)(att + h * 16);
#pragma unroll
        for (int i2 = 0; i2 < 4; ++i2) at4[i2] = atp[i2];
    }

    float alpha[KNN];
#pragma unroll
    for (int k = 0; k < KNN; ++k) {
        const uint4* xlp = (const uint4*)(xl1b + (size_t)j[k] * 64 + h * 16);
        f4 xlv[4];
        u4_to_f8(xlp[0], &xlv[0]);
        u4_to_f8(xlp[1], &xlv[2]);
        float s = 0.f;
#pragma unroll
        for (int i2 = 0; i2 < 4; ++i2) {
            const f4 m = xlv[i2] + xr4[i2];
#pragma unroll
            for (int c = 0; c < 4; ++c) {
                float mm = m[c];
                mm = mm > 0.f ? mm : 0.2f * mm;   // leaky_relu(., 0.2)
                s += mm * at4[i2][c];
            }
        }
        alpha[k] = s;
    }
    float amax = alpha[0];
#pragma unroll
    for (int k = 1; k < KNN; ++k) amax = fmaxf(amax, alpha[k]);
    float e[KNN];
    float denom = 0.f;
#pragma unroll
    for (int k = 0; k < KNN; ++k) { e[k] = expf(alpha[k] - amax); denom += e[k]; }
    const float rd = 1.f / denom;

    f4 o4[4];
#pragma unroll
    for (int i2 = 0; i2 < 4; ++i2) o4[i2] = 0.f;
#pragma unroll
    for (int k = 0; k < KNN; ++k) {
        const uint4* xlp = (const uint4*)(xl1b + (size_t)j[k] * 64 + h * 16);
        f4 xlv[4];
        u4_to_f8(xlp[0], &xlv[0]);
        u4_to_f8(xlp[1], &xlv[2]);
#pragma unroll
        for (int i2 = 0; i2 < 4; ++i2) o4[i2] += e[k] * xlv[i2];
    }
    const f4* bp = (const f4*)(bias + h * 16);
    short8 r0, r1;
#pragma unroll
    for (int i2 = 0; i2 < 4; ++i2) {
        const f4 v = o4[i2] * rd + bp[i2];
#pragma unroll
        for (int c = 0; c < 4; ++c) {
            const unsigned short bv = f2bf(v[c]);
            const int e4 = i2 * 4 + c;
            if (e4 < 8) r0[e4] = (short)bv; else r1[e4 - 8] = (short)bv;
        }
    }
    short8* hp = (short8*)(h1b + node * 64 + h * 16);
    hp[0] = r0;
    hp[1] = r1;
}

// ---------------------------------------------------------------------------
// Kernel 4a: pack Wl2||Wr2 into bf16 MFMA B-fragment layout.
// ---------------------------------------------------------------------------
__global__ __launch_bounds__(256) void wprep_kernel(const float* __restrict__ Wl,
                                                    const float* __restrict__ Wr,
                                                    unsigned short* __restrict__ wbf) {
    const int t = blockIdx.x * 256 + threadIdx.x;   // 64*256 = 16384
    const int k = t >> 8;
    const int n = t & 255;
    const float v = (n < 128) ? Wl[k * 128 + n] : Wr[k * 128 + (n - 128)];
    wbf[((k >> 3) * 256 + n) * 8 + (k & 7)] = f2bf(v);
}

// ---------------------------------------------------------------------------
// Kernel 4b: lin2 via MFMA (mapping verified round 8). Outputs bf16.
// ---------------------------------------------------------------------------
__global__ __launch_bounds__(256) void lin2_kernel(const unsigned short* __restrict__ h1b,
                                                   const unsigned short* __restrict__ wbf,
                                                   const float* __restrict__ bl,
                                                   const float* __restrict__ br,
                                                   unsigned short* __restrict__ xl2b,
                                                   unsigned short* __restrict__ xr2b) {
    const int tid = threadIdx.x;
    const int lane = tid & 63;
    const int w = tid >> 6;
    const size_t node0 = (size_t)blockIdx.x * 16;
    const int lm = lane & 15, lk = lane >> 4;

    const short8* hp = (const short8*)h1b;
    const short8 a0 = hp[(node0 + lm) * 8 + lk];
    const short8 a1 = hp[(node0 + lm) * 8 + lk + 4];

    const short8* wp = (const short8*)wbf;
#pragma unroll
    for (int t = 0; t < 4; ++t) {
        const int col = w * 64 + t * 16 + lm;
        const float bias = (col < 128) ? bl[col] : br[col - 128];
        f4 acc = {bias, bias, bias, bias};
        const short8 b0 = wp[lk * 256 + col];
        const short8 b1 = wp[(lk + 4) * 256 + col];
        acc = __builtin_amdgcn_mfma_f32_16x16x32_bf16(a0, b0, acc, 0, 0, 0);
        acc = __builtin_amdgcn_mfma_f32_16x16x32_bf16(a1, b1, acc, 0, 0, 0);
        unsigned short* dst = (col < 128) ? (xl2b + col) : (xr2b + (col - 128));
#pragma unroll
        for (int r = 0; r < 4; ++r)
            dst[(node0 + lk * 4 + r) * 128] = f2bf(acc[r]);
    }
}

// ---------------------------------------------------------------------------
// Kernel 5: GATv2 layer-2 aggregation + pooling — round-12/14 structure
// (one thread per (node, head, half), 16 ch, two-pass, butterfly pool),
// pair-converts. XCD-swizzled. No min-waves bound (round-15 spill lesson).
// ---------------------------------------------------------------------------
__global__ __launch_bounds__(256) void agg2_pool_kernel(const unsigned short* __restrict__ xl2b,
                                                        const unsigned short* __restrict__ xr2b,
                                                        const int* __restrict__ knn,
                                                        const float* __restrict__ att,
                                                        float* __restrict__ partial) {
    const int x = blockIdx.x & 7;
    const int i = blockIdx.x >> 3;
    const int graph = x * 32 + (i >> 4);
    const int sub = i & 15;
    const int tid = threadIdx.x;
    const int lane = tid & 63;
    const int wv = tid >> 6;
    const int n8 = lane >> 3;
    const int h = (lane >> 1) & 3;
    const int half = lane & 1;
    const size_t node = (size_t)graph * NPG + sub * 32 + wv * 8 + n8;
    const int co = h * 32 + half * 16;

    const int* nb = knn + node * KNN;
    int j[KNN];
#pragma unroll
    for (int k = 0; k < KNN; ++k) j[k] = nb[k];

    f4 xr4[4], at4[4];
    {
        const uint4* xrp = (const uint4*)(xr2b + node * 128 + co);
        u4_to_f8(xrp[0], &xr4[0]);
        u4_to_f8(xrp[1], &xr4[2]);
        const f4* atp = (const f4*)(att + co);
#pragma unroll
        for (int i2 = 0; i2 < 4; ++i2) at4[i2] = atp[i2];
    }

    float alpha[KNN];
#pragma unroll
    for (int k = 0; k < KNN; ++k) {
        const uint4* xlp = (const uint4*)(xl2b + (size_t)j[k] * 128 + co);
        f4 xlv[4];
        u4_to_f8(xlp[0], &xlv[0]);
        u4_to_f8(xlp[1], &xlv[2]);
        float s = 0.f;
#pragma unroll
        for (int i2 = 0; i2 < 4; ++i2) {
            const f4 m = xlv[i2] + xr4[i2];
#pragma unroll
            for (int c = 0; c < 4; ++c) {
                float mm = m[c];
                mm = mm > 0.f ? mm : 0.2f * mm;
                s += mm * at4[i2][c];
            }
        }
        alpha[k] = s + __shfl_xor(s, 1);
    }
    float amax = alpha[0];
#pragma unroll
    for (int k = 1; k < KNN; ++k) amax = fmaxf(amax, alpha[k]);
    float e[KNN];
    float denom = 0.f;
#pragma unroll
    for (int k = 0; k < KNN; ++k) { e[k] = expf(alpha[k] - amax); denom += e[k]; }
    const float rd = 1.f / denom;

    f4 o4[4];
#pragma unroll
    for (int i2 = 0; i2 < 4; ++i2) o4[i2] = 0.f;
#pragma unroll
    for (int k = 0; k < KNN; ++k) {
        const uint4* xlp = (const uint4*)(xl2b + (size_t)j[k] * 128 + co);
        f4 xlv[4];
        u4_to_f8(xlp[0], &xlv[0]);
        u4_to_f8(xlp[1], &xlv[2]);
#pragma unroll
        for (int i2 = 0; i2 < 4; ++i2) o4[i2] += e[k] * xlv[i2];
    }
#pragma unroll
    for (int i2 = 0; i2 < 4; ++i2) o4[i2] *= rd;

#pragma unroll
    for (int m = 8; m <= 32; m <<= 1) {
#pragma unroll
        for (int i2 = 0; i2 < 4; ++i2) {
#pragma unroll
            for (int c = 0; c < 4; ++c) o4[i2][c] += __shfl_xor(o4[i2][c], m);
        }
    }
    if (n8 == 0) {
        f4* pp = (f4*)(partial + ((size_t)(graph * 16 + sub) * 4 + wv) * 128 + co);
#pragma unroll
        for (int i2 = 0; i2 < 4; ++i2) pp[i2] = o4[i2];
    }
}

// ---------------------------------------------------------------------------
// Kernel 6: stage-2 pool. One block per graph; 64 partials, /NPG, +bias2.
// ---------------------------------------------------------------------------
__global__ __launch_bounds__(128) void pool2_kernel(const float* __restrict__ partial,
                                                    const float* __restrict__ bias,
                                                    float* __restrict__ out) {
    const int g = blockIdx.x;
    const int c = threadIdx.x;
    float s = 0.f;
#pragma unroll
    for (int b = 0; b < 64; ++b) s += partial[(size_t)(g * 64 + b) * 128 + c];
    out[g * 128 + c] = s * (1.f / 512.f) + bias[c];
}

extern "C" void kernel_launch(void* const* d_in, const int* in_sizes, int n_in,
                              void* d_out, int out_size, void* d_ws, size_t ws_size,
                              hipStream_t stream) {
    const float* pos   = (const float*)d_in[0];
    const float* x     = (const float*)d_in[1];
    const float* Wl1   = (const float*)d_in[3];
    const float* bl1   = (const float*)d_in[4];
    const float* Wr1   = (const float*)d_in[5];
    const float* br1   = (const float*)d_in[6];
    const float* att1  = (const float*)d_in[7];
    const float* bias1 = (const float*)d_in[8];
    const float* Wl2   = (const float*)d_in[9];
    const float* bl2   = (const float*)d_in[10];
    const float* Wr2   = (const float*)d_in[11];
    const float* br2   = (const float*)d_in[12];
    const float* att2  = (const float*)d_in[13];
    const float* bias2 = (const float*)d_in[14];
    float* out = (float*)d_out;

    // Workspace layout (liveness-overlapped):
    //   [0,          3670016)  knn [N][7] i32                    (live: all)
    //   [3670016,   20447232)  xl1b bf16 [N][64]  (dead after agg1)
    //   [20447232,  37224448)  xr1b bf16 [N][64]  (dead after agg1)
    //   [37224448,  54001664)  h1b  bf16 [N][64]  (dead after lin2;
    //        partial [16384][128] f32 = 8.4MB overlays here)
    //   [54001664,  54034432)  wbf bf16 32KB
    //   [88080384, 121634816)  xl2b bf16 [N][128]
    //   [121634816,155189248)  xr2b bf16 [N][128]
    char* ws = (char*)d_ws;
    int*            knn  = (int*)(ws + 0);
    unsigned short* xl1b = (unsigned short*)(ws + 3670016);
    unsigned short* xr1b = (unsigned short*)(ws + 20447232);
    unsigned short* h1b  = (unsigned short*)(ws + 37224448);
    unsigned short* wbf  = (unsigned short*)(ws + 54001664);
    unsigned short* xl2b = (unsigned short*)(ws + 88080384);
    unsigned short* xr2b = (unsigned short*)(ws + 121634816);
    float*          partial = (float*)(ws + 37224448); // over dead h1b

    knn_kernel<<<B_GRAPHS * 4, 512, 0, stream>>>(pos, knn);
    lin1_kernel<<<(N_NODES * 16) / 256, 256, 0, stream>>>(x, Wl1, bl1, Wr1, br1, xl1b, xr1b);
    wprep_kernel<<<64, 256, 0, stream>>>(Wl2, Wr2, wbf);
    agg1_kernel<<<(N_NODES * 4) / 256, 256, 0, stream>>>(xl1b, xr1b, knn, att1, bias1, h1b);
    lin2_kernel<<<N_NODES / 16, 256, 0, stream>>>(h1b, wbf, bl2, br2, xl2b, xr2b);
    agg2_pool_kernel<<<N_NODES / 32, 256, 0, stream>>>(xl2b, xr2b, knn, att2, partial);
    pool2_kernel<<<B_GRAPHS, 128, 0, stream>>>(partial, bias2, out);
}

// Round 17
// 152.822 us; speedup vs baseline: 3.4767x; 1.0041x over previous
//
#include <hip/hip_runtime.h>
#include <hip/hip_bf16.h>

#define N_NODES 131072
#define B_GRAPHS 256
#define NPG 512
#define KNN 7
#define HEADS 4

using f4 = __attribute__((ext_vector_type(4))) float;
using short8 = __attribute__((ext_vector_type(8))) short;  // 8 bf16 (4 VGPRs)

__device__ __forceinline__ unsigned short f2bf(float f) {   // RNE f32->bf16
    unsigned u = __builtin_bit_cast(unsigned, f);
    u += 0x7FFFu + ((u >> 16) & 1u);
    return (unsigned short)(u >> 16);
}

// 8 packed bf16 (uint4) -> 8 f32 in sequential channel order, 8 VALU ops.
__device__ __forceinline__ void u4_to_f8(const uint4 u, f4* out) {
    out[0][0] = __builtin_bit_cast(float, u.x << 16);
    out[0][1] = __builtin_bit_cast(float, u.x & 0xFFFF0000u);
    out[0][2] = __builtin_bit_cast(float, u.y << 16);
    out[0][3] = __builtin_bit_cast(float, u.y & 0xFFFF0000u);
    out[1][0] = __builtin_bit_cast(float, u.z << 16);
    out[1][1] = __builtin_bit_cast(float, u.z & 0xFFFF0000u);
    out[1][2] = __builtin_bit_cast(float, u.w << 16);
    out[1][3] = __builtin_bit_cast(float, u.w & 0xFFFF0000u);
}

__device__ __forceinline__ unsigned med3u(unsigned a, unsigned b, unsigned c) {
    unsigned r;
    asm("v_med3_u32 %0, %1, %2, %3" : "=v"(r) : "v"(a), "v"(b), "v"(c));
    return r;
}

// insert key into ascending top-7: valid because b[] is sorted, so
// max(b[i-1], min(b[i], k)) == med3(b[i-1], b[i], k). 1 umin + 6 med3 = 7 ops.
#define INS7(B, KEY) { \
    const unsigned _k = (KEY); \
    const unsigned n0 = min(B[0], _k); \
    const unsigned n1 = med3u(B[0], B[1], _k); \
    const unsigned n2 = med3u(B[1], B[2], _k); \
    const unsigned n3 = med3u(B[2], B[3], _k); \
    const unsigned n4 = med3u(B[3], B[4], _k); \
    const unsigned n5 = med3u(B[4], B[5], _k); \
    const unsigned n6 = med3u(B[5], B[6], _k); \
    B[0]=n0; B[1]=n1; B[2]=n2; B[3]=n3; B[4]=n4; B[5]=n5; B[6]=n6; }

// ---------------------------------------------------------------------------
// Kernel 1: kNN, 4-way candidate split (verified round 12).
// ---------------------------------------------------------------------------
__global__ __launch_bounds__(512) void knn_kernel(const float* __restrict__ pos,
                                                  int* __restrict__ knn) {
    __shared__ f4 sp[NPG];
    __shared__ unsigned mk[3][128][7];
    const int tid = threadIdx.x;
    const int g = blockIdx.x >> 2;
    const int qh = blockIdx.x & 3;
    const int ch = tid >> 7;                 // candidate chunk 0..3
    const int ql = tid & 127;
    const int q = qh * 128 + ql;             // local query index

    const float* p = pos + (size_t)g * NPG * 3;
    {
        f4 v; v[0] = p[tid * 3 + 0]; v[1] = p[tid * 3 + 1]; v[2] = p[tid * 3 + 2]; v[3] = 0.f;
        sp[tid] = v;
    }
    __syncthreads();

    const f4 qp = sp[q];
    unsigned b[7];
#pragma unroll
    for (int i = 0; i < 7; ++i) b[i] = 0xFFFFFFFFu;

    const int j0 = ch << 7;
#pragma unroll 8
    for (int j = 0; j < 128; ++j) {
        const int jj = j0 + j;                  // wave-uniform
        const f4 c = sp[jj];                    // LDS broadcast
        const float dx = qp[0] - c[0];
        const float dy = qp[1] - c[1];
        const float dz = qp[2] - c[2];
        const float d2 = dx * dx + dy * dy + dz * dz;
        unsigned key = (__builtin_bit_cast(unsigned, d2) & 0xFFFFFE00u) | (unsigned)jj;
        key = (jj == q) ? 0xFFFFFFFFu : key;    // no self-loop
        INS7(b, key)
    }

    if (ch != 0) {
        unsigned* m = mk[ch - 1][ql];
#pragma unroll
        for (int i = 0; i < 7; ++i) m[i] = b[i];
    }
    __syncthreads();
    if (ch == 0) {
#pragma unroll
        for (int cc = 0; cc < 3; ++cc) {
            const unsigned* m = mk[cc][ql];
#pragma unroll
            for (int i = 0; i < 7; ++i) INS7(b, m[i])
        }
        const int base = (g * NPG + q) * KNN;
        const int off = g * NPG;
#pragma unroll
        for (int i = 0; i < 7; ++i) knn[base + i] = off + (int)(b[i] & 0x1FFu);
    }
}
#undef INS7

// ---------------------------------------------------------------------------
// Kernel 2: fused lin1. Both xl1 and xr1 -> bf16 (validated round 13).
// ---------------------------------------------------------------------------
__global__ __launch_bounds__(256) void lin1_kernel(const float* __restrict__ x,
                                                   const float* __restrict__ Wl,
                                                   const float* __restrict__ bl,
                                                   const float* __restrict__ Wr,
                                                   const float* __restrict__ br,
                                                   unsigned short* __restrict__ xl1b,
                                                   unsigned short* __restrict__ xr1b) {
    const int idx = blockIdx.x * 256 + threadIdx.x;   // N*16
    const int c4 = idx & 15;
    const size_t node = (size_t)(idx >> 4);
    const float* xrow = x + node * 10;
    f4 al = ((const f4*)bl)[c4];
    f4 ar = ((const f4*)br)[c4];
#pragma unroll
    for (int k = 0; k < 10; ++k) {
        const float xv = xrow[k];
        al += xv * ((const f4*)(Wl + k * 64))[c4];
        ar += xv * ((const f4*)(Wr + k * 64))[c4];
    }
    uint2 pl, pr;
    pl.x = (unsigned)f2bf(al[0]) | ((unsigned)f2bf(al[1]) << 16);
    pl.y = (unsigned)f2bf(al[2]) | ((unsigned)f2bf(al[3]) << 16);
    pr.x = (unsigned)f2bf(ar[0]) | ((unsigned)f2bf(ar[1]) << 16);
    pr.y = (unsigned)f2bf(ar[2]) | ((unsigned)f2bf(ar[3]) << 16);
    ((uint2*)xl1b)[node * 16 + c4] = pl;
    ((uint2*)xr1b)[node * 16 + c4] = pr;
}

// ---------------------------------------------------------------------------
// Kernel 3: GATv2 layer-1 aggregation. Round-14 lane mapping (one thread per
// (node, head), 16 ch) but SINGLE gather: neighbor rows kept in uint4 regs
// across the softmax (7 x 4 = 28 VGPR, stays under the 128 cliff).
// XCD-swizzled. No min-waves bound (round-15 spill lesson).
// ---------------------------------------------------------------------------
__global__ __launch_bounds__(256) void agg1_kernel(const unsigned short* __restrict__ xl1b,
                                                   const unsigned short* __restrict__ xr1b,
                                                   const int* __restrict__ knn,
                                                   const float* __restrict__ att,
                                                   const float* __restrict__ bias,
                                                   unsigned short* __restrict__ h1b) {
    const int x = blockIdx.x & 7;
    const int i = blockIdx.x >> 3;
    const int graph = x * 32 + (i >> 3);
    const int sub = i & 7;
    const int tid = threadIdx.x;
    const int h = tid & 3;
    const size_t node = (size_t)graph * NPG + sub * 64 + (tid >> 2);

    const int* nb = knn + node * KNN;
    int j[KNN];
#pragma unroll
    for (int k = 0; k < KNN; ++k) j[k] = nb[k];

    f4 xr4[4], at4[4];
    {
        const uint4* xrp = (const uint4*)(xr1b + node * 64 + h * 16);
        u4_to_f8(xrp[0], &xr4[0]);
        u4_to_f8(xrp[1], &xr4[2]);
        const f4* atp = (const f4*)(att + h * 16);
#pragma unroll
        for (int i2 = 0; i2 < 4; ++i2) at4[i2] = atp[i2];
    }

    uint4 xv0[KNN], xv1[KNN];
    float alpha[KNN];
#pragma unroll
    for (int k = 0; k < KNN; ++k) {
        const uint4* xlp = (const uint4*)(xl1b + (size_t)j[k] * 64 + h * 16);
        xv0[k] = xlp[0];
        xv1[k] = xlp[1];
        f4 xlv[4];
        u4_to_f8(xv0[k], &xlv[0]);
        u4_to_f8(xv1[k], &xlv[2]);
        float s = 0.f;
#pragma unroll
        for (int i2 = 0; i2 < 4; ++i2) {
            const f4 m = xlv[i2] + xr4[i2];
#pragma unroll
            for (int c = 0; c < 4; ++c) {
                float mm = m[c];
                mm = mm > 0.f ? mm : 0.2f * mm;   // leaky_relu(., 0.2)
                s += mm * at4[i2][c];
            }
        }
        alpha[k] = s;
    }
    float amax = alpha[0];
#pragma unroll
    for (int k = 1; k < KNN; ++k) amax = fmaxf(amax, alpha[k]);
    float e[KNN];
    float denom = 0.f;
#pragma unroll
    for (int k = 0; k < KNN; ++k) { e[k] = expf(alpha[k] - amax); denom += e[k]; }
    const float rd = 1.f / denom;

    f4 o4[4];
#pragma unroll
    for (int i2 = 0; i2 < 4; ++i2) o4[i2] = 0.f;
#pragma unroll
    for (int k = 0; k < KNN; ++k) {
        f4 xlv[4];
        u4_to_f8(xv0[k], &xlv[0]);               // from registers, no reload
        u4_to_f8(xv1[k], &xlv[2]);
#pragma unroll
        for (int i2 = 0; i2 < 4; ++i2) o4[i2] += e[k] * xlv[i2];
    }
    const f4* bp = (const f4*)(bias + h * 16);
    short8 r0, r1;
#pragma unroll
    for (int i2 = 0; i2 < 4; ++i2) {
        const f4 v = o4[i2] * rd + bp[i2];
#pragma unroll
        for (int c = 0; c < 4; ++c) {
            const unsigned short bv = f2bf(v[c]);
            const int e4 = i2 * 4 + c;
            if (e4 < 8) r0[e4] = (short)bv; else r1[e4 - 8] = (short)bv;
        }
    }
    short8* hp = (short8*)(h1b + node * 64 + h * 16);
    hp[0] = r0;
    hp[1] = r1;
}

// ---------------------------------------------------------------------------
// Kernel 4a: pack Wl2||Wr2 into bf16 MFMA B-fragment layout.
// ---------------------------------------------------------------------------
__global__ __launch_bounds__(256) void wprep_kernel(const float* __restrict__ Wl,
                                                    const float* __restrict__ Wr,
                                                    unsigned short* __restrict__ wbf) {
    const int t = blockIdx.x * 256 + threadIdx.x;   // 64*256 = 16384
    const int k = t >> 8;
    const int n = t & 255;
    const float v = (n < 128) ? Wl[k * 128 + n] : Wr[k * 128 + (n - 128)];
    wbf[((k >> 3) * 256 + n) * 8 + (k & 7)] = f2bf(v);
}

// ---------------------------------------------------------------------------
// Kernel 4b: lin2 via MFMA (mapping verified round 8). Outputs bf16.
// ---------------------------------------------------------------------------
__global__ __launch_bounds__(256) void lin2_kernel(const unsigned short* __restrict__ h1b,
                                                   const unsigned short* __restrict__ wbf,
                                                   const float* __restrict__ bl,
                                                   const float* __restrict__ br,
                                                   unsigned short* __restrict__ xl2b,
                                                   unsigned short* __restrict__ xr2b) {
    const int tid = threadIdx.x;
    const int lane = tid & 63;
    const int w = tid >> 6;
    const size_t node0 = (size_t)blockIdx.x * 16;
    const int lm = lane & 15, lk = lane >> 4;

    const short8* hp = (const short8*)h1b;
    const short8 a0 = hp[(node0 + lm) * 8 + lk];
    const short8 a1 = hp[(node0 + lm) * 8 + lk + 4];

    const short8* wp = (const short8*)wbf;
#pragma unroll
    for (int t = 0; t < 4; ++t) {
        const int col = w * 64 + t * 16 + lm;
        const float bias = (col < 128) ? bl[col] : br[col - 128];
        f4 acc = {bias, bias, bias, bias};
        const short8 b0 = wp[lk * 256 + col];
        const short8 b1 = wp[(lk + 4) * 256 + col];
        acc = __builtin_amdgcn_mfma_f32_16x16x32_bf16(a0, b0, acc, 0, 0, 0);
        acc = __builtin_amdgcn_mfma_f32_16x16x32_bf16(a1, b1, acc, 0, 0, 0);
        unsigned short* dst = (col < 128) ? (xl2b + col) : (xr2b + (col - 128));
#pragma unroll
        for (int r = 0; r < 4; ++r)
            dst[(node0 + lk * 4 + r) * 128] = f2bf(acc[r]);
    }
}

// ---------------------------------------------------------------------------
// Kernel 5: GATv2 layer-2 aggregation + pooling. Round-14 lane mapping
// (one thread per (node, head, half), 16 ch) but SINGLE gather: neighbor
// rows in uint4 regs across the softmax. Butterfly pool. XCD-swizzled.
// ---------------------------------------------------------------------------
__global__ __launch_bounds__(256) void agg2_pool_kernel(const unsigned short* __restrict__ xl2b,
                                                        const unsigned short* __restrict__ xr2b,
                                                        const int* __restrict__ knn,
                                                        const float* __restrict__ att,
                                                        float* __restrict__ partial) {
    const int x = blockIdx.x & 7;
    const int i = blockIdx.x >> 3;
    const int graph = x * 32 + (i >> 4);
    const int sub = i & 15;
    const int tid = threadIdx.x;
    const int lane = tid & 63;
    const int wv = tid >> 6;
    const int n8 = lane >> 3;
    const int h = (lane >> 1) & 3;
    const int half = lane & 1;
    const size_t node = (size_t)graph * NPG + sub * 32 + wv * 8 + n8;
    const int co = h * 32 + half * 16;

    const int* nb = knn + node * KNN;
    int j[KNN];
#pragma unroll
    for (int k = 0; k < KNN; ++k) j[k] = nb[k];

    f4 xr4[4], at4[4];
    {
        const uint4* xrp = (const uint4*)(xr2b + node * 128 + co);
        u4_to_f8(xrp[0], &xr4[0]);
        u4_to_f8(xrp[1], &xr4[2]);
        const f4* atp = (const f4*)(att + co);
#pragma unroll
        for (int i2 = 0; i2 < 4; ++i2) at4[i2] = atp[i2];
    }

    uint4 xv0[KNN], xv1[KNN];
    float alpha[KNN];
#pragma unroll
    for (int k = 0; k < KNN; ++k) {
        const uint4* xlp = (const uint4*)(xl2b + (size_t)j[k] * 128 + co);
        xv0[k] = xlp[0];
        xv1[k] = xlp[1];
        f4 xlv[4];
        u4_to_f8(xv0[k], &xlv[0]);
        u4_to_f8(xv1[k], &xlv[2]);
        float s = 0.f;
#pragma unroll
        for (int i2 = 0; i2 < 4; ++i2) {
            const f4 m = xlv[i2] + xr4[i2];
#pragma unroll
            for (int c = 0; c < 4; ++c) {
                float mm = m[c];
                mm = mm > 0.f ? mm : 0.2f * mm;
                s += mm * at4[i2][c];
            }
        }
        alpha[k] = s + __shfl_xor(s, 1);
    }
    float amax = alpha[0];
#pragma unroll
    for (int k = 1; k < KNN; ++k) amax = fmaxf(amax, alpha[k]);
    float e[KNN];
    float denom = 0.f;
#pragma unroll
    for (int k = 0; k < KNN; ++k) { e[k] = expf(alpha[k] - amax); denom += e[k]; }
    const float rd = 1.f / denom;

    f4 o4[4];
#pragma unroll
    for (int i2 = 0; i2 < 4; ++i2) o4[i2] = 0.f;
#pragma unroll
    for (int k = 0; k < KNN; ++k) {
        f4 xlv[4];
        u4_to_f8(xv0[k], &xlv[0]);               // from registers, no reload
        u4_to_f8(xv1[k], &xlv[2]);
#pragma unroll
        for (int i2 = 0; i2 < 4; ++i2) o4[i2] += e[k] * xlv[i2];
    }
#pragma unroll
    for (int i2 = 0; i2 < 4; ++i2) o4[i2] *= rd;

#pragma unroll
    for (int m = 8; m <= 32; m <<= 1) {
#pragma unroll
        for (int i2 = 0; i2 < 4; ++i2) {
#pragma unroll
            for (int c = 0; c < 4; ++c) o4[i2][c] += __shfl_xor(o4[i2][c], m);
        }
    }
    if (n8 == 0) {
        f4* pp = (f4*)(partial + ((size_t)(graph * 16 + sub) * 4 + wv) * 128 + co);
#pragma unroll
        for (int i2 = 0; i2 < 4; ++i2) pp[i2] = o4[i2];
    }
}

// ---------------------------------------------------------------------------
// Kernel 6: stage-2 pool. One block per graph; 64 partials, /NPG, +bias2.
// ---------------------------------------------------------------------------
__global__ __launch_bounds__(128) void pool2_kernel(const float* __restrict__ partial,
                                                    const float* __restrict__ bias,
                                                    float* __restrict__ out) {
    const int g = blockIdx.x;
    const int c = threadIdx.x;
    float s = 0.f;
#pragma unroll
    for (int b = 0; b < 64; ++b) s += partial[(size_t)(g * 64 + b) * 128 + c];
    out[g * 128 + c] = s * (1.f / 512.f) + bias[c];
}

extern "C" void kernel_launch(void* const* d_in, const int* in_sizes, int n_in,
                              void* d_out, int out_size, void* d_ws, size_t ws_size,
                              hipStream_t stream) {
    const float* pos   = (const float*)d_in[0];
    const float* x     = (const float*)d_in[1];
    const float* Wl1   = (const float*)d_in[3];
    const float* bl1   = (const float*)d_in[4];
    const float* Wr1   = (const float*)d_in[5];
    const float* br1   = (const float*)d_in[6];
    const float* att1  = (const float*)d_in[7];
    const float* bias1 = (const float*)d_in[8];
    const float* Wl2   = (const float*)d_in[9];
    const float* bl2   = (const float*)d_in[10];
    const float* Wr2   = (const float*)d_in[11];
    const float* br2   = (const float*)d_in[12];
    const float* att2  = (const float*)d_in[13];
    const float* bias2 = (const float*)d_in[14];
    float* out = (float*)d_out;

    // Workspace layout (liveness-overlapped):
    //   [0,          3670016)  knn [N][7] i32                    (live: all)
    //   [3670016,   20447232)  xl1b bf16 [N][64]  (dead after agg1)
    //   [20447232,  37224448)  xr1b bf16 [N][64]  (dead after agg1)
    //   [37224448,  54001664)  h1b  bf16 [N][64]  (dead after lin2;
    //        partial [16384][128] f32 = 8.4MB overlays here)
    //   [54001664,  54034432)  wbf bf16 32KB
    //   [88080384, 121634816)  xl2b bf16 [N][128]
    //   [121634816,155189248)  xr2b bf16 [N][128]
    char* ws = (char*)d_ws;
    int*            knn  = (int*)(ws + 0);
    unsigned short* xl1b = (unsigned short*)(ws + 3670016);
    unsigned short* xr1b = (unsigned short*)(ws + 20447232);
    unsigned short* h1b  = (unsigned short*)(ws + 37224448);
    unsigned short* wbf  = (unsigned short*)(ws + 54001664);
    unsigned short* xl2b = (unsigned short*)(ws + 88080384);
    unsigned short* xr2b = (unsigned short*)(ws + 121634816);
    float*          partial = (float*)(ws + 37224448); // over dead h1b

    knn_kernel<<<B_GRAPHS * 4, 512, 0, stream>>>(pos, knn);
    lin1_kernel<<<(N_NODES * 16) / 256, 256, 0, stream>>>(x, Wl1, bl1, Wr1, br1, xl1b, xr1b);
    wprep_kernel<<<64, 256, 0, stream>>>(Wl2, Wr2, wbf);
    agg1_kernel<<<(N_NODES * 4) / 256, 256, 0, stream>>>(xl1b, xr1b, knn, att1, bias1, h1b);
    lin2_kernel<<<N_NODES / 16, 256, 0, stream>>>(h1b, wbf, bl2, br2, xl2b, xr2b);
    agg2_pool_kernel<<<N_NODES / 32, 256, 0, stream>>>(xl2b, xr2b, knn, att2, partial);
    pool2_kernel<<<B_GRAPHS, 128, 0, stream>>>(partial, bias2, out);
}

// Round 18
// 150.977 us; speedup vs baseline: 3.5192x; 1.0122x over previous
//
#include <hip/hip_runtime.h>
#include <hip/hip_bf16.h>

#define N_NODES 131072
#define B_GRAPHS 256
#define NPG 512
#define KNN 7
#define HEADS 4

using f4 = __attribute__((ext_vector_type(4))) float;
using f2 = __attribute__((ext_vector_type(2))) float;
using short8 = __attribute__((ext_vector_type(8))) short;  // 8 bf16 (4 VGPRs)

__device__ __forceinline__ unsigned short f2bf(float f) {   // RNE f32->bf16
    unsigned u = __builtin_bit_cast(unsigned, f);
    u += 0x7FFFu + ((u >> 16) & 1u);
    return (unsigned short)(u >> 16);
}

// 8 packed bf16 (uint4) -> 4 x f2 (sequential channel pairs), 8 VALU ops.
__device__ __forceinline__ void u4_to_pk(const uint4 u, f2* out) {
    out[0][0] = __builtin_bit_cast(float, u.x << 16);
    out[0][1] = __builtin_bit_cast(float, u.x & 0xFFFF0000u);
    out[1][0] = __builtin_bit_cast(float, u.y << 16);
    out[1][1] = __builtin_bit_cast(float, u.y & 0xFFFF0000u);
    out[2][0] = __builtin_bit_cast(float, u.z << 16);
    out[2][1] = __builtin_bit_cast(float, u.z & 0xFFFF0000u);
    out[3][0] = __builtin_bit_cast(float, u.w << 16);
    out[3][1] = __builtin_bit_cast(float, u.w & 0xFFFF0000u);
}

__device__ __forceinline__ unsigned med3u(unsigned a, unsigned b, unsigned c) {
    unsigned r;
    asm("v_med3_u32 %0, %1, %2, %3" : "=v"(r) : "v"(a), "v"(b), "v"(c));
    return r;
}

// insert key into ascending top-7: valid because b[] is sorted, so
// max(b[i-1], min(b[i], k)) == med3(b[i-1], b[i], k). 1 umin + 6 med3 = 7 ops.
#define INS7(B, KEY) { \
    const unsigned _k = (KEY); \
    const unsigned n0 = min(B[0], _k); \
    const unsigned n1 = med3u(B[0], B[1], _k); \
    const unsigned n2 = med3u(B[1], B[2], _k); \
    const unsigned n3 = med3u(B[2], B[3], _k); \
    const unsigned n4 = med3u(B[3], B[4], _k); \
    const unsigned n5 = med3u(B[4], B[5], _k); \
    const unsigned n6 = med3u(B[5], B[6], _k); \
    B[0]=n0; B[1]=n1; B[2]=n2; B[3]=n3; B[4]=n4; B[5]=n5; B[6]=n6; }

// ---------------------------------------------------------------------------
// Kernel 1: kNN, 4-way candidate split (verified round 12).
// ---------------------------------------------------------------------------
__global__ __launch_bounds__(512) void knn_kernel(const float* __restrict__ pos,
                                                  int* __restrict__ knn) {
    __shared__ f4 sp[NPG];
    __shared__ unsigned mk[3][128][7];
    const int tid = threadIdx.x;
    const int g = blockIdx.x >> 2;
    const int qh = blockIdx.x & 3;
    const int ch = tid >> 7;                 // candidate chunk 0..3
    const int ql = tid & 127;
    const int q = qh * 128 + ql;             // local query index

    const float* p = pos + (size_t)g * NPG * 3;
    {
        f4 v; v[0] = p[tid * 3 + 0]; v[1] = p[tid * 3 + 1]; v[2] = p[tid * 3 + 2]; v[3] = 0.f;
        sp[tid] = v;
    }
    __syncthreads();

    const f4 qp = sp[q];
    unsigned b[7];
#pragma unroll
    for (int i = 0; i < 7; ++i) b[i] = 0xFFFFFFFFu;

    const int j0 = ch << 7;
#pragma unroll 8
    for (int j = 0; j < 128; ++j) {
        const int jj = j0 + j;                  // wave-uniform
        const f4 c = sp[jj];                    // LDS broadcast
        const float dx = qp[0] - c[0];
        const float dy = qp[1] - c[1];
        const float dz = qp[2] - c[2];
        const float d2 = dx * dx + dy * dy + dz * dz;
        unsigned key = (__builtin_bit_cast(unsigned, d2) & 0xFFFFFE00u) | (unsigned)jj;
        key = (jj == q) ? 0xFFFFFFFFu : key;    // no self-loop
        INS7(b, key)
    }

    if (ch != 0) {
        unsigned* m = mk[ch - 1][ql];
#pragma unroll
        for (int i = 0; i < 7; ++i) m[i] = b[i];
    }
    __syncthreads();
    if (ch == 0) {
#pragma unroll
        for (int cc = 0; cc < 3; ++cc) {
            const unsigned* m = mk[cc][ql];
#pragma unroll
            for (int i = 0; i < 7; ++i) INS7(b, m[i])
        }
        const int base = (g * NPG + q) * KNN;
        const int off = g * NPG;
#pragma unroll
        for (int i = 0; i < 7; ++i) knn[base + i] = off + (int)(b[i] & 0x1FFu);
    }
}
#undef INS7

// ---------------------------------------------------------------------------
// Kernel 2: fused lin1. Both xl1 and xr1 -> bf16 (validated round 13).
// ---------------------------------------------------------------------------
__global__ __launch_bounds__(256) void lin1_kernel(const float* __restrict__ x,
                                                   const float* __restrict__ Wl,
                                                   const float* __restrict__ bl,
                                                   const float* __restrict__ Wr,
                                                   const float* __restrict__ br,
                                                   unsigned short* __restrict__ xl1b,
                                                   unsigned short* __restrict__ xr1b) {
    const int idx = blockIdx.x * 256 + threadIdx.x;   // N*16
    const int c4 = idx & 15;
    const size_t node = (size_t)(idx >> 4);
    const float* xrow = x + node * 10;
    f4 al = ((const f4*)bl)[c4];
    f4 ar = ((const f4*)br)[c4];
#pragma unroll
    for (int k = 0; k < 10; ++k) {
        const float xv = xrow[k];
        al += xv * ((const f4*)(Wl + k * 64))[c4];
        ar += xv * ((const f4*)(Wr + k * 64))[c4];
    }
    uint2 pl, pr;
    pl.x = (unsigned)f2bf(al[0]) | ((unsigned)f2bf(al[1]) << 16);
    pl.y = (unsigned)f2bf(al[2]) | ((unsigned)f2bf(al[3]) << 16);
    pr.x = (unsigned)f2bf(ar[0]) | ((unsigned)f2bf(ar[1]) << 16);
    pr.y = (unsigned)f2bf(ar[2]) | ((unsigned)f2bf(ar[3]) << 16);
    ((uint2*)xl1b)[node * 16 + c4] = pl;
    ((uint2*)xr1b)[node * 16 + c4] = pr;
}

// ---------------------------------------------------------------------------
// Kernel 3: GATv2 layer-1 aggregation. Round-14 lane mapping, register-
// resident neighbor rows (round 17), inner loops restructured as float2
// packed math (v_pk_add/mul/max/fma candidates). leaky_relu as
// max(m, 0.2m) — exactly equal to (m>0 ? m : 0.2m). XCD-swizzled.
// ---------------------------------------------------------------------------
__global__ __launch_bounds__(256) void agg1_kernel(const unsigned short* __restrict__ xl1b,
                                                   const unsigned short* __restrict__ xr1b,
                                                   const int* __restrict__ knn,
                                                   const float* __restrict__ att,
                                                   const float* __restrict__ bias,
                                                   unsigned short* __restrict__ h1b) {
    const int x = blockIdx.x & 7;
    const int i = blockIdx.x >> 3;
    const int graph = x * 32 + (i >> 3);
    const int sub = i & 7;
    const int tid = threadIdx.x;
    const int h = tid & 3;
    const size_t node = (size_t)graph * NPG + sub * 64 + (tid >> 2);

    const int* nb = knn + node * KNN;
    int j[KNN];
#pragma unroll
    for (int k = 0; k < KNN; ++k) j[k] = nb[k];

    f2 xr2[8], at2[8];
    {
        const uint4* xrp = (const uint4*)(xr1b + node * 64 + h * 16);
        u4_to_pk(xrp[0], &xr2[0]);
        u4_to_pk(xrp[1], &xr2[4]);
        const f2* atp = (const f2*)(att + h * 16);
#pragma unroll
        for (int g2 = 0; g2 < 8; ++g2) at2[g2] = atp[g2];
    }

    uint4 xv0[KNN], xv1[KNN];
    float alpha[KNN];
#pragma unroll
    for (int k = 0; k < KNN; ++k) {
        const uint4* xlp = (const uint4*)(xl1b + (size_t)j[k] * 64 + h * 16);
        xv0[k] = xlp[0];
        xv1[k] = xlp[1];
        f2 x2[8];
        u4_to_pk(xv0[k], &x2[0]);
        u4_to_pk(xv1[k], &x2[4]);
        f2 s2 = {0.f, 0.f};
#pragma unroll
        for (int g2 = 0; g2 < 8; ++g2) {
            const f2 m = x2[g2] + xr2[g2];
            const f2 lr = __builtin_elementwise_max(m, m * 0.2f);  // leaky_relu
            s2 += lr * at2[g2];
        }
        alpha[k] = s2[0] + s2[1];
    }
    float amax = alpha[0];
#pragma unroll
    for (int k = 1; k < KNN; ++k) amax = fmaxf(amax, alpha[k]);
    float e[KNN];
    float denom = 0.f;
#pragma unroll
    for (int k = 0; k < KNN; ++k) { e[k] = expf(alpha[k] - amax); denom += e[k]; }
    const float rd = 1.f / denom;

    f2 o2[8];
#pragma unroll
    for (int g2 = 0; g2 < 8; ++g2) o2[g2] = (f2){0.f, 0.f};
#pragma unroll
    for (int k = 0; k < KNN; ++k) {
        f2 x2[8];
        u4_to_pk(xv0[k], &x2[0]);               // from registers, no reload
        u4_to_pk(xv1[k], &x2[4]);
        const f2 ek = {e[k], e[k]};
#pragma unroll
        for (int g2 = 0; g2 < 8; ++g2) o2[g2] += ek * x2[g2];
    }
    const f2* bp = (const f2*)(bias + h * 16);
    const f2 rd2 = {rd, rd};
    short8 r0, r1;
#pragma unroll
    for (int g2 = 0; g2 < 8; ++g2) {
        const f2 v = o2[g2] * rd2 + bp[g2];
        const int e0 = g2 * 2;
        const unsigned short b0v = f2bf(v[0]);
        const unsigned short b1v = f2bf(v[1]);
        if (e0 < 8) { r0[e0] = (short)b0v; r0[e0 + 1] = (short)b1v; }
        else        { r1[e0 - 8] = (short)b0v; r1[e0 - 7] = (short)b1v; }
    }
    short8* hp = (short8*)(h1b + node * 64 + h * 16);
    hp[0] = r0;
    hp[1] = r1;
}

// ---------------------------------------------------------------------------
// Kernel 4a: pack Wl2||Wr2 into bf16 MFMA B-fragment layout.
// ---------------------------------------------------------------------------
__global__ __launch_bounds__(256) void wprep_kernel(const float* __restrict__ Wl,
                                                    const float* __restrict__ Wr,
                                                    unsigned short* __restrict__ wbf) {
    const int t = blockIdx.x * 256 + threadIdx.x;   // 64*256 = 16384
    const int k = t >> 8;
    const int n = t & 255;
    const float v = (n < 128) ? Wl[k * 128 + n] : Wr[k * 128 + (n - 128)];
    wbf[((k >> 3) * 256 + n) * 8 + (k & 7)] = f2bf(v);
}

// ---------------------------------------------------------------------------
// Kernel 4b: lin2 via MFMA (mapping verified round 8). Outputs bf16.
// ---------------------------------------------------------------------------
__global__ __launch_bounds__(256) void lin2_kernel(const unsigned short* __restrict__ h1b,
                                                   const unsigned short* __restrict__ wbf,
                                                   const float* __restrict__ bl,
                                                   const float* __restrict__ br,
                                                   unsigned short* __restrict__ xl2b,
                                                   unsigned short* __restrict__ xr2b) {
    const int tid = threadIdx.x;
    const int lane = tid & 63;
    const int w = tid >> 6;
    const size_t node0 = (size_t)blockIdx.x * 16;
    const int lm = lane & 15, lk = lane >> 4;

    const short8* hp = (const short8*)h1b;
    const short8 a0 = hp[(node0 + lm) * 8 + lk];
    const short8 a1 = hp[(node0 + lm) * 8 + lk + 4];

    const short8* wp = (const short8*)wbf;
#pragma unroll
    for (int t = 0; t < 4; ++t) {
        const int col = w * 64 + t * 16 + lm;
        const float bias = (col < 128) ? bl[col] : br[col - 128];
        f4 acc = {bias, bias, bias, bias};
        const short8 b0 = wp[lk * 256 + col];
        const short8 b1 = wp[(lk + 4) * 256 + col];
        acc = __builtin_amdgcn_mfma_f32_16x16x32_bf16(a0, b0, acc, 0, 0, 0);
        acc = __builtin_amdgcn_mfma_f32_16x16x32_bf16(a1, b1, acc, 0, 0, 0);
        unsigned short* dst = (col < 128) ? (xl2b + col) : (xr2b + (col - 128));
#pragma unroll
        for (int r = 0; r < 4; ++r)
            dst[(node0 + lk * 4 + r) * 128] = f2bf(acc[r]);
    }
}

// ---------------------------------------------------------------------------
// Kernel 5: GATv2 layer-2 aggregation + pooling. Round-14 lane mapping,
// register-resident rows, float2 packed math. Butterfly pool. XCD-swizzled.
// ---------------------------------------------------------------------------
__global__ __launch_bounds__(256) void agg2_pool_kernel(const unsigned short* __restrict__ xl2b,
                                                        const unsigned short* __restrict__ xr2b,
                                                        const int* __restrict__ knn,
                                                        const float* __restrict__ att,
                                                        float* __restrict__ partial) {
    const int x = blockIdx.x & 7;
    const int i = blockIdx.x >> 3;
    const int graph = x * 32 + (i >> 4);
    const int sub = i & 15;
    const int tid = threadIdx.x;
    const int lane = tid & 63;
    const int wv = tid >> 6;
    const int n8 = lane >> 3;
    const int h = (lane >> 1) & 3;
    const int half = lane & 1;
    const size_t node = (size_t)graph * NPG + sub * 32 + wv * 8 + n8;
    const int co = h * 32 + half * 16;

    const int* nb = knn + node * KNN;
    int j[KNN];
#pragma unroll
    for (int k = 0; k < KNN; ++k) j[k] = nb[k];

    f2 xr2[8], at2[8];
    {
        const uint4* xrp = (const uint4*)(xr2b + node * 128 + co);
        u4_to_pk(xrp[0], &xr2[0]);
        u4_to_pk(xrp[1], &xr2[4]);
        const f2* atp = (const f2*)(att + co);
#pragma unroll
        for (int g2 = 0; g2 < 8; ++g2) at2[g2] = atp[g2];
    }

    uint4 xv0[KNN], xv1[KNN];
    float alpha[KNN];
#pragma unroll
    for (int k = 0; k < KNN; ++k) {
        const uint4* xlp = (const uint4*)(xl2b + (size_t)j[k] * 128 + co);
        xv0[k] = xlp[0];
        xv1[k] = xlp[1];
        f2 x2[8];
        u4_to_pk(xv0[k], &x2[0]);
        u4_to_pk(xv1[k], &x2[4]);
        f2 s2 = {0.f, 0.f};
#pragma unroll
        for (int g2 = 0; g2 < 8; ++g2) {
            const f2 m = x2[g2] + xr2[g2];
            const f2 lr = __builtin_elementwise_max(m, m * 0.2f);  // leaky_relu
            s2 += lr * at2[g2];
        }
        const float s = s2[0] + s2[1];
        alpha[k] = s + __shfl_xor(s, 1);
    }
    float amax = alpha[0];
#pragma unroll
    for (int k = 1; k < KNN; ++k) amax = fmaxf(amax, alpha[k]);
    float e[KNN];
    float denom = 0.f;
#pragma unroll
    for (int k = 0; k < KNN; ++k) { e[k] = expf(alpha[k] - amax); denom += e[k]; }
    const float rd = 1.f / denom;

    f2 o2[8];
#pragma unroll
    for (int g2 = 0; g2 < 8; ++g2) o2[g2] = (f2){0.f, 0.f};
#pragma unroll
    for (int k = 0; k < KNN; ++k) {
        f2 x2[8];
        u4_to_pk(xv0[k], &x2[0]);               // from registers, no reload
        u4_to_pk(xv1[k], &x2[4]);
        const f2 ek = {e[k], e[k]};
#pragma unroll
        for (int g2 = 0; g2 < 8; ++g2) o2[g2] += ek * x2[g2];
    }
    const f2 rd2 = {rd, rd};
#pragma unroll
    for (int g2 = 0; g2 < 8; ++g2) o2[g2] *= rd2;

    // pool butterfly over the wave's 8 nodes
#pragma unroll
    for (int m = 8; m <= 32; m <<= 1) {
#pragma unroll
        for (int g2 = 0; g2 < 8; ++g2) {
#pragma unroll
            for (int c = 0; c < 2; ++c) o2[g2][c] += __shfl_xor(o2[g2][c], m);
        }
    }
    if (n8 == 0) {
        f2* pp = (f2*)(partial + ((size_t)(graph * 16 + sub) * 4 + wv) * 128 + co);
#pragma unroll
        for (int g2 = 0; g2 < 8; ++g2) pp[g2] = o2[g2];
    }
}

// ---------------------------------------------------------------------------
// Kernel 6: stage-2 pool. One block per graph; 64 partials, /NPG, +bias2.
// ---------------------------------------------------------------------------
__global__ __launch_bounds__(128) void pool2_kernel(const float* __restrict__ partial,
                                                    const float* __restrict__ bias,
                                                    float* __restrict__ out) {
    const int g = blockIdx.x;
    const int c = threadIdx.x;
    float s = 0.f;
#pragma unroll
    for (int b = 0; b < 64; ++b) s += partial[(size_t)(g * 64 + b) * 128 + c];
    out[g * 128 + c] = s * (1.f / 512.f) + bias[c];
}

extern "C" void kernel_launch(void* const* d_in, const int* in_sizes, int n_in,
                              void* d_out, int out_size, void* d_ws, size_t ws_size,
                              hipStream_t stream) {
    const float* pos   = (const float*)d_in[0];
    const float* x     = (const float*)d_in[1];
    const float* Wl1   = (const float*)d_in[3];
    const float* bl1   = (const float*)d_in[4];
    const float* Wr1   = (const float*)d_in[5];
    const float* br1   = (const float*)d_in[6];
    const float* att1  = (const float*)d_in[7];
    const float* bias1 = (const float*)d_in[8];
    const float* Wl2   = (const float*)d_in[9];
    const float* bl2   = (const float*)d_in[10];
    const float* Wr2   = (const float*)d_in[11];
    const float* br2   = (const float*)d_in[12];
    const float* att2  = (const float*)d_in[13];
    const float* bias2 = (const float*)d_in[14];
    float* out = (float*)d_out;

    // Workspace layout (liveness-overlapped):
    //   [0,          3670016)  knn [N][7] i32                    (live: all)
    //   [3670016,   20447232)  xl1b bf16 [N][64]  (dead after agg1)
    //   [20447232,  37224448)  xr1b bf16 [N][64]  (dead after agg1)
    //   [37224448,  54001664)  h1b  bf16 [N][64]  (dead after lin2;
    //        partial [16384][128] f32 = 8.4MB overlays here)
    //   [54001664,  54034432)  wbf bf16 32KB
    //   [88080384, 121634816)  xl2b bf16 [N][128]
    //   [121634816,155189248)  xr2b bf16 [N][128]
    char* ws = (char*)d_ws;
    int*            knn  = (int*)(ws + 0);
    unsigned short* xl1b = (unsigned short*)(ws + 3670016);
    unsigned short* xr1b = (unsigned short*)(ws + 20447232);
    unsigned short* h1b  = (unsigned short*)(ws + 37224448);
    unsigned short* wbf  = (unsigned short*)(ws + 54001664);
    unsigned short* xl2b = (unsigned short*)(ws + 88080384);
    unsigned short* xr2b = (unsigned short*)(ws + 121634816);
    float*          partial = (float*)(ws + 37224448); // over dead h1b

    knn_kernel<<<B_GRAPHS * 4, 512, 0, stream>>>(pos, knn);
    lin1_kernel<<<(N_NODES * 16) / 256, 256, 0, stream>>>(x, Wl1, bl1, Wr1, br1, xl1b, xr1b);
    wprep_kernel<<<64, 256, 0, stream>>>(Wl2, Wr2, wbf);
    agg1_kernel<<<(N_NODES * 4) / 256, 256, 0, stream>>>(xl1b, xr1b, knn, att1, bias1, h1b);
    lin2_kernel<<<N_NODES / 16, 256, 0, stream>>>(h1b, wbf, bl2, br2, xl2b, xr2b);
    agg2_pool_kernel<<<N_NODES / 32, 256, 0, stream>>>(xl2b, xr2b, knn, att2, partial);
    pool2_kernel<<<B_GRAPHS, 128, 0, stream>>>(partial, bias2, out);
}